// Round 1
// baseline (143.465 us; speedup 1.0000x reference)
//
#include <hip/hip_runtime.h>
#include <hip/hip_bf16.h>
#include <math.h>

#define B_ 128
#define IN_ 1024
#define D_ 128
#define H_ 512
#define S_ 256
#define RB 32   // rows of w_tilde per block in the big kernel

__device__ __forceinline__ float softplusf(float x) {
  // numerically stable: max(x,0) + log1p(exp(-|x|))
  return fmaxf(x, 0.f) + log1pf(expf(-fabsf(x)));
}

// sum over all 256 threads; every thread returns the total
__device__ __forceinline__ float blockReduceSum256(float v, float* red) {
  #pragma unroll
  for (int o = 32; o > 0; o >>= 1) v += __shfl_down(v, o);
  const int lane = threadIdx.x & 63, wid = threadIdx.x >> 6;
  __syncthreads();              // protect red reuse across calls
  if (lane == 0) red[wid] = v;
  __syncthreads();
  return red[0] + red[1] + red[2] + red[3];
}

// Per-batch small terms: log_pxw, log_pwx, f_zw, and zpre+b1 (staged for kernelB).
// One block per batch element b, 256 threads.
__global__ __launch_bounds__(256) void kernelA(
    const float* __restrict__ x, const float* __restrict__ w,
    const float* __restrict__ z, const float* __restrict__ W,
    const float* __restrict__ bvec, const float* __restrict__ cvec,
    const float* __restrict__ W1, const float* __restrict__ b1,
    const float* __restrict__ W2, const float* __restrict__ b2,
    float* __restrict__ zb1, float* __restrict__ scalars) {
  const int b = blockIdx.x;
  const int t = threadIdx.x;
  __shared__ float xs[IN_];
  __shared__ float ws[D_];
  __shared__ float zs[D_];
  __shared__ float p2[256];
  __shared__ float red[4];

  for (int i = t; i < IN_; i += 256) xs[i] = x[b * IN_ + i];
  if (t < D_) { ws[t] = w[b * D_ + t]; zs[t] = z[b * D_ + t]; }
  __syncthreads();

  // ---- log_pwx: logits2[d] = sum_i x[i]*W[i][d] + b[d] ----
  {
    const int d = t & 127, half = t >> 7;
    float s = 0.f;
    const int i0 = half * 512;
    for (int i = i0; i < i0 + 512; ++i) s = fmaf(xs[i], W[i * D_ + d], s);
    p2[t] = s;
    __syncthreads();
    float term = 0.f;
    if (t < D_) {
      const float lg = p2[t] + p2[t + 128] + bvec[t];
      term = ws[t] * lg - softplusf(lg);
    }
    const float tot = blockReduceSum256(term, red);
    if (t == 0) scalars[B_ + b] = tot;   // log_pwx
  }

  // ---- log_pxw: logits1[i] = sum_d w[d]*W[i][d] + c[i] ----
  {
    float term = 0.f;
    #pragma unroll
    for (int ii = 0; ii < 4; ++ii) {
      const int i = t + ii * 256;
      float lg = cvec[i];
      const float* __restrict__ row = W + i * D_;
      #pragma unroll 8
      for (int d = 0; d < D_; ++d) lg = fmaf(ws[d], row[d], lg);
      term += xs[i] * lg - softplusf(lg);
    }
    const float tot = blockReduceSum256(term, red);
    if (t == 0) scalars[b] = tot;        // log_pxw
  }

  // ---- zpre (+b1) stored for kernelB; f_zw = relu(zpre+wpre)@W2 + b2 ----
  {
    float fpart = 0.f;
    #pragma unroll
    for (int hh = 0; hh < 2; ++hh) {
      const int h = t + hh * 256;
      float zp = b1[h], wp = 0.f;
      const float* __restrict__ row = W1 + h * (2 * D_);
      #pragma unroll 8
      for (int d = 0; d < D_; ++d) {
        zp = fmaf(zs[d], row[d], zp);
        wp = fmaf(ws[d], row[D_ + d], wp);
      }
      zb1[b * H_ + h] = zp;
      fpart += fmaxf(zp + wp, 0.f) * W2[h];
    }
    const float tot = blockReduceSum256(fpart, red);
    if (t == 0) scalars[2 * B_ + b] = tot + b2[0];  // f_zw
  }
}

// Transpose the w-half of W1 into W1wT[d][h] for coalesced GEMM loads.
__global__ __launch_bounds__(256) void kernelT(const float* __restrict__ W1,
                                               float* __restrict__ W1wT) {
  const int idx = blockIdx.x * 256 + threadIdx.x;   // 65536 total
  const int d = idx >> 9, h = idx & 511;
  W1wT[idx] = W1[h * (2 * D_) + D_ + d];
}

// The big fused GEMM: f_tilde[s][b] = relu(zb1[b][:] + w_tilde[s][b]@W1w^T) . W2 + b2
// Block handles 32 s-rows of one batch column b. 256 threads:
//   tidh = t&127 -> h chunk of 4 (h0 = tidh*4), tidr = t>>7 -> row-group of 16.
__global__ __launch_bounds__(256) void kernelB(
    const float* __restrict__ wt, const float* __restrict__ W1wT,
    const float* __restrict__ zb1, const float* __restrict__ W2,
    const float* __restrict__ b2, float* __restrict__ ftT) {
  const int blk = blockIdx.x;          // 1024 blocks
  const int b = blk & (B_ - 1);
  const int sc = blk >> 7;             // 0..7
  const int t = threadIdx.x;
  const int tidh = t & 127;
  const int tidr = t >> 7;             // 0..1
  const int h0 = tidh * 4;

  __shared__ float a[RB][D_];          // 16 KB
  __shared__ float red[4][16];

  // stage A-tile: 32 rows x 128 (each thread 4x float4)
  {
    const int r = t >> 3;              // 0..31
    const int dq = (t & 7) * 16;       // 0..112
    const float* __restrict__ src = wt + (size_t)((sc * RB + r) * B_ + b) * D_ + dq;
    float4 v0 = *(const float4*)(src + 0);
    float4 v1 = *(const float4*)(src + 4);
    float4 v2 = *(const float4*)(src + 8);
    float4 v3 = *(const float4*)(src + 12);
    *(float4*)&a[r][dq + 0]  = v0;
    *(float4*)&a[r][dq + 4]  = v1;
    *(float4*)&a[r][dq + 8]  = v2;
    *(float4*)&a[r][dq + 12] = v3;
  }

  float zreg[4], w2reg[4];
  #pragma unroll
  for (int j = 0; j < 4; ++j) {
    zreg[j]  = zb1[b * H_ + h0 + j];
    w2reg[j] = W2[h0 + j];
  }
  __syncthreads();

  float acc[16][4];
  #pragma unroll
  for (int r = 0; r < 16; ++r)
    #pragma unroll
    for (int j = 0; j < 4; ++j) acc[r][j] = 0.f;

  const int rbase = tidr * 16;
  for (int d0 = 0; d0 < D_; d0 += 4) {
    const float4 wv0 = *(const float4*)&W1wT[(d0 + 0) * H_ + h0];
    const float4 wv1 = *(const float4*)&W1wT[(d0 + 1) * H_ + h0];
    const float4 wv2 = *(const float4*)&W1wT[(d0 + 2) * H_ + h0];
    const float4 wv3 = *(const float4*)&W1wT[(d0 + 3) * H_ + h0];
    #pragma unroll
    for (int r = 0; r < 16; ++r) {
      const float4 av = *(const float4*)&a[rbase + r][d0];
      acc[r][0] = fmaf(av.x, wv0.x, fmaf(av.y, wv1.x, fmaf(av.z, wv2.x, fmaf(av.w, wv3.x, acc[r][0]))));
      acc[r][1] = fmaf(av.x, wv0.y, fmaf(av.y, wv1.y, fmaf(av.z, wv2.y, fmaf(av.w, wv3.y, acc[r][1]))));
      acc[r][2] = fmaf(av.x, wv0.z, fmaf(av.y, wv1.z, fmaf(av.z, wv2.z, fmaf(av.w, wv3.z, acc[r][2]))));
      acc[r][3] = fmaf(av.x, wv0.w, fmaf(av.y, wv1.w, fmaf(av.z, wv2.w, fmaf(av.w, wv3.w, acc[r][3]))));
    }
  }

  // epilogue: relu + W2 dot, reduce h across the 64 lanes of each wave
  #pragma unroll
  for (int r = 0; r < 16; ++r) {
    float v = 0.f;
    #pragma unroll
    for (int j = 0; j < 4; ++j)
      v += fmaxf(acc[r][j] + zreg[j], 0.f) * w2reg[j];
    #pragma unroll
    for (int o = 1; o < 64; o <<= 1) v += __shfl_xor(v, o);
    if ((t & 63) == 0) red[t >> 6][r] = v;
  }
  __syncthreads();
  // waves 0+1 -> rows 0..15 ; waves 2+3 -> rows 16..31
  if (t < RB) {
    const int rg = t >> 4, r = t & 15;
    const float v = red[rg * 2][r] + red[rg * 2 + 1][r] + b2[0];
    ftT[b * S_ + sc * RB + rg * 16 + r] = v;
  }
}

// logsumexp over S per batch + final combine
__global__ __launch_bounds__(256) void kernelC(
    const float* __restrict__ ftT, const float* __restrict__ scalars,
    float* __restrict__ out) {
  const int b = blockIdx.x, t = threadIdx.x;
  __shared__ float red[4];
  __shared__ float red2[4];
  const float v = ftT[b * S_ + t];
  float m = v;
  #pragma unroll
  for (int o = 1; o < 64; o <<= 1) m = fmaxf(m, __shfl_xor(m, o));
  const int lane = t & 63, wid = t >> 6;
  if (lane == 0) red[wid] = m;
  __syncthreads();
  m = fmaxf(fmaxf(red[0], red[1]), fmaxf(red[2], red[3]));
  float e = expf(v - m);
  #pragma unroll
  for (int o = 1; o < 64; o <<= 1) e += __shfl_xor(e, o);
  if (lane == 0) red2[wid] = e;
  __syncthreads();
  if (t == 0) {
    const float tot = red2[0] + red2[1] + red2[2] + red2[3];
    const float logZ = m + logf(tot) - logf((float)S_) + (float)D_ * logf(2.f);
    const float pxw = scalars[b];
    const float pwx = scalars[B_ + b];
    const float fzw = scalars[2 * B_ + b];
    const float r_wz = fminf(fzw - logZ, 0.f);
    out[b] = -(pxw - pwx + r_wz);
  }
}

extern "C" void kernel_launch(void* const* d_in, const int* in_sizes, int n_in,
                              void* d_out, int out_size, void* d_ws, size_t ws_size,
                              hipStream_t stream) {
  const float* x    = (const float*)d_in[0];
  // d_in[1] = y, unused by the reference computation
  const float* w    = (const float*)d_in[2];
  const float* z    = (const float*)d_in[3];
  const float* wt   = (const float*)d_in[4];
  const float* W    = (const float*)d_in[5];
  const float* bvec = (const float*)d_in[6];
  const float* cvec = (const float*)d_in[7];
  const float* W1   = (const float*)d_in[8];
  const float* b1   = (const float*)d_in[9];
  const float* W2   = (const float*)d_in[10];
  const float* b2   = (const float*)d_in[11];

  float* ws_f   = (float*)d_ws;
  float* zb1    = ws_f;                 // B*H   = 65536 floats
  float* W1wT   = ws_f + 65536;         // D*H   = 65536 floats
  float* ftT    = ws_f + 131072;        // B*S   = 32768 floats
  float* scalars= ws_f + 163840;        // 3*B   = 384 floats

  float* out = (float*)d_out;

  hipLaunchKernelGGL(kernelA, dim3(B_), dim3(256), 0, stream,
                     x, w, z, W, bvec, cvec, W1, b1, W2, b2, zb1, scalars);
  hipLaunchKernelGGL(kernelT, dim3(256), dim3(256), 0, stream, W1, W1wT);
  hipLaunchKernelGGL(kernelB, dim3((S_ / RB) * B_), dim3(256), 0, stream,
                     wt, W1wT, zb1, W2, b2, ftT);
  hipLaunchKernelGGL(kernelC, dim3(B_), dim3(256), 0, stream, ftT, scalars, out);
}

// Round 2
// 69.879 us; speedup vs baseline: 2.0530x; 2.0530x over previous
//
#include <hip/hip_runtime.h>
#include <hip/hip_bf16.h>
#include <math.h>

#define B_ 128
#define IN_ 1024
#define D_ 128
#define H_ 512
#define S_ 256

typedef __attribute__((ext_vector_type(8))) short short8v;
typedef __attribute__((ext_vector_type(8))) unsigned short ushort8v;
typedef __attribute__((ext_vector_type(4))) float f32x4;

__device__ __forceinline__ float softplusf(float x) {
  return fmaxf(x, 0.f) + log1pf(expf(-fabsf(x)));
}

__device__ __forceinline__ unsigned short f2bf(float f) {
  unsigned u = __float_as_uint(f);
  unsigned r = (u + 0x7fff + ((u >> 16) & 1)) >> 16;   // RNE
  return (unsigned short)r;
}

// sum over all 256 threads; thread 0 gets the total
__device__ __forceinline__ float blockReduceSum256(float v, float* red) {
  #pragma unroll
  for (int o = 32; o > 0; o >>= 1) v += __shfl_down(v, o);
  const int lane = threadIdx.x & 63, wid = threadIdx.x >> 6;
  if (lane == 0) red[wid] = v;
  __syncthreads();
  return red[0] + red[1] + red[2] + red[3];
}

// ---------------- W1 w-half -> bf16 [H][D] ----------------
__global__ __launch_bounds__(256) void Kconv(const float* __restrict__ W1,
                                             unsigned short* __restrict__ W1wb) {
  const int idx = blockIdx.x * 256 + threadIdx.x;   // 65536
  const int h = idx >> 7, d = idx & 127;
  W1wb[idx] = f2bf(W1[(size_t)h * 256 + 128 + d]);
}

// ---------------- log_pwx: one block per b, 1024 threads, K-split x8 ----------------
__global__ __launch_bounds__(1024) void K_pwx(const float* __restrict__ x,
                                              const float* __restrict__ w,
                                              const float* __restrict__ W,
                                              const float* __restrict__ bvec,
                                              float* __restrict__ scal_pwx) {
  const int b = blockIdx.x;
  const int t = threadIdx.x;
  __shared__ float xs[IN_];
  __shared__ float p2[8][128];
  __shared__ float ws_[128];
  __shared__ float red[128];
  xs[t] = x[b * IN_ + t];
  if (t < 128) ws_[t] = w[b * 128 + t];
  __syncthreads();
  const int d = t & 127, ks = t >> 7;
  float s = 0.f;
  const int i0 = ks * 128;
  #pragma unroll 8
  for (int i = i0; i < i0 + 128; ++i) s = fmaf(xs[i], W[(size_t)i * 128 + d], s);
  p2[ks][d] = s;
  __syncthreads();
  if (t < 128) {
    float lg = bvec[t];
    #pragma unroll
    for (int k2 = 0; k2 < 8; ++k2) lg += p2[k2][t];
    red[t] = ws_[t] * lg - softplusf(lg);
  }
  __syncthreads();
  for (int o = 64; o > 0; o >>= 1) {
    if (t < o) red[t] += red[t + o];
    __syncthreads();
  }
  if (t == 0) scal_pwx[b] = red[0];
}

// ---------------- log_pxw: block = (b, i-chunk of 256) ----------------
__global__ __launch_bounds__(256) void K_pxw(const float* __restrict__ x,
                                             const float* __restrict__ w,
                                             const float* __restrict__ W,
                                             const float* __restrict__ cvec,
                                             float* __restrict__ pxw_part) {
  const int b = blockIdx.x >> 2, ic = blockIdx.x & 3;
  const int t = threadIdx.x;
  const int i = ic * 256 + t;
  __shared__ float ws_[128];
  __shared__ float red[4];
  if (t < 128) ws_[t] = w[b * 128 + t];
  __syncthreads();
  const float4* __restrict__ row = (const float4*)(W + (size_t)i * 128);
  float a0 = 0.f, a1 = 0.f, a2 = 0.f, a3 = 0.f;
  #pragma unroll
  for (int q = 0; q < 32; ++q) {
    const float4 v = row[q];
    a0 = fmaf(v.x, ws_[4 * q + 0], a0);
    a1 = fmaf(v.y, ws_[4 * q + 1], a1);
    a2 = fmaf(v.z, ws_[4 * q + 2], a2);
    a3 = fmaf(v.w, ws_[4 * q + 3], a3);
  }
  const float lg = cvec[i] + ((a0 + a1) + (a2 + a3));
  const float term = x[b * IN_ + i] * lg - softplusf(lg);
  const float tot = blockReduceSum256(term, red);
  if (t == 0) pxw_part[b * 4 + ic] = tot;
}

// ---------------- zpre(+b1) + f_zw partials: block = (b-quad, h-chunk of 64) ----------------
__global__ __launch_bounds__(256) void K_zw(const float* __restrict__ z,
                                            const float* __restrict__ w,
                                            const float* __restrict__ W1,
                                            const float* __restrict__ b1,
                                            const float* __restrict__ W2,
                                            float* __restrict__ zb1,
                                            float* __restrict__ fzw_part) {
  const int bq = blockIdx.x >> 3;   // 0..31
  const int hc = blockIdx.x & 7;    // 0..7
  const int t = threadIdx.x;
  const int bs = t >> 6;            // wave id = b-sub
  const int hl = t & 63;
  const int b = bq * 4 + bs;
  const int h = hc * 64 + hl;
  __shared__ float zs[4][128];
  __shared__ float ws2[4][128];
  if (t < 512) {
    const int bb = t >> 7, d = t & 127;
    zs[bb][d] = z[(bq * 4 + bb) * 128 + d];
    const int t2 = t + 512;   // reuse same threads for w: t2 in [512,1024) maps bb2,d2
  }
  // stage w too (256 threads, 512 elems each array -> 2 elems per thread per array)
  {
    const int e0 = t, e1 = t + 256;
    ws2[e0 >> 7][e0 & 127] = w[(bq * 4 + (e0 >> 7)) * 128 + (e0 & 127)];
    ws2[e1 >> 7][e1 & 127] = w[(bq * 4 + (e1 >> 7)) * 128 + (e1 & 127)];
    const int f1 = t + 256;
    zs[f1 >> 7][f1 & 127] = z[(bq * 4 + (f1 >> 7)) * 128 + (f1 & 127)];
  }
  __syncthreads();
  const float4* __restrict__ row = (const float4*)(W1 + (size_t)h * 256);
  float zp = b1[h], wp = 0.f;
  #pragma unroll
  for (int q = 0; q < 32; ++q) {
    const float4 v = row[q];
    zp = fmaf(v.x, zs[bs][4 * q + 0], zp);
    zp = fmaf(v.y, zs[bs][4 * q + 1], zp);
    zp = fmaf(v.z, zs[bs][4 * q + 2], zp);
    zp = fmaf(v.w, zs[bs][4 * q + 3], zp);
  }
  #pragma unroll
  for (int q = 32; q < 64; ++q) {
    const float4 v = row[q];
    wp = fmaf(v.x, ws2[bs][4 * q - 128 + 0], wp);
    wp = fmaf(v.y, ws2[bs][4 * q - 128 + 1], wp);
    wp = fmaf(v.z, ws2[bs][4 * q - 128 + 2], wp);
    wp = fmaf(v.w, ws2[bs][4 * q - 128 + 3], wp);
  }
  zb1[(size_t)b * H_ + h] = zp;
  float fp = fmaxf(zp + wp, 0.f) * W2[h];
  #pragma unroll
  for (int o = 1; o < 64; o <<= 1) fp += __shfl_xor(fp, o);
  if (hl == 0) fzw_part[b * 8 + hc] = fp;
}

// ---------------- big GEMM via MFMA: f_tilde ----------------
// block = (b, s-chunk of 32). 4 waves: (mtile = wave&1 -> rows, nh = wave>>1 -> h half)
__global__ __launch_bounds__(256) void K_mfma(const float* __restrict__ wt,
                                              const unsigned short* __restrict__ W1wb,
                                              const float* __restrict__ zb1,
                                              const float* __restrict__ W2,
                                              const float* __restrict__ b2,
                                              float* __restrict__ ftT) {
  const int blk = blockIdx.x;
  const int b = blk & (B_ - 1);
  const int sc = blk >> 7;
  const int s0 = sc * 32;
  const int t = threadIdx.x;
  const int lane = t & 63, wave = t >> 6;
  const int mtile = wave & 1, nh = wave >> 1;

  __shared__ unsigned short atile[32 * 128];   // XOR-swizzled bf16 tile, 8 KB
  __shared__ float zb1s[H_];
  __shared__ float w2s[H_];
  __shared__ float red[2][32];

  // stage zb1[b][:], W2[:]
  zb1s[t] = zb1[(size_t)b * H_ + t];
  zb1s[256 + t] = zb1[(size_t)b * H_ + 256 + t];
  w2s[t] = W2[t];
  w2s[256 + t] = W2[256 + t];

  // stage A tile: 32 rows x 128 d, fp32 -> bf16, swizzle 16B granules: g ^= row&15
  {
    const int r = t >> 3;              // 0..31
    const int gp = (t & 7) * 2;        // granule pair
    const float* __restrict__ src = wt + ((size_t)(s0 + r) * B_ + b) * D_;
    #pragma unroll
    for (int gg = 0; gg < 2; ++gg) {
      const int g = gp + gg;
      const float4 v0 = *(const float4*)(src + g * 8);
      const float4 v1 = *(const float4*)(src + g * 8 + 4);
      ushort8v u;
      u[0] = f2bf(v0.x); u[1] = f2bf(v0.y); u[2] = f2bf(v0.z); u[3] = f2bf(v0.w);
      u[4] = f2bf(v1.x); u[5] = f2bf(v1.y); u[6] = f2bf(v1.z); u[7] = f2bf(v1.w);
      *(ushort8v*)&atile[r * 128 + ((g ^ (r & 15)) << 3)] = u;
    }
  }
  __syncthreads();

  // A fragments: row = mtile*16 + (lane&15), k = ks*32 + (lane>>4)*8 + j
  short8v afr[4];
  const int arow = mtile * 16 + (lane & 15);
  #pragma unroll
  for (int ks = 0; ks < 4; ++ks) {
    const int g = ks * 4 + (lane >> 4);
    afr[ks] = *(const short8v*)&atile[arow * 128 + ((g ^ (arow & 15)) << 3)];
  }

  float fsum0 = 0.f, fsum1 = 0.f, fsum2 = 0.f, fsum3 = 0.f;
  const int hl = lane & 15;
  const int kgrp = (lane >> 4) * 8;
  #pragma unroll 4
  for (int nt = 0; nt < 16; ++nt) {
    const int hrow = nh * 256 + nt * 16 + hl;
    f32x4 acc = {0.f, 0.f, 0.f, 0.f};
    #pragma unroll
    for (int ks = 0; ks < 4; ++ks) {
      const short8v bfr = *(const short8v*)(W1wb + (size_t)hrow * 128 + ks * 32 + kgrp);
      acc = __builtin_amdgcn_mfma_f32_16x16x32_bf16(afr[ks], bfr, acc, 0, 0, 0);
    }
    const float zv = zb1s[hrow], wv = w2s[hrow];
    fsum0 += fmaxf(acc[0] + zv, 0.f) * wv;
    fsum1 += fmaxf(acc[1] + zv, 0.f) * wv;
    fsum2 += fmaxf(acc[2] + zv, 0.f) * wv;
    fsum3 += fmaxf(acc[3] + zv, 0.f) * wv;
  }
  // reduce over the 16 h-columns (lanes differing in bits 0..3)
  #pragma unroll
  for (int o = 1; o < 16; o <<= 1) {
    fsum0 += __shfl_xor(fsum0, o);
    fsum1 += __shfl_xor(fsum1, o);
    fsum2 += __shfl_xor(fsum2, o);
    fsum3 += __shfl_xor(fsum3, o);
  }
  if (hl == 0) {
    const int rbase = mtile * 16 + (lane >> 4) * 4;
    red[nh][rbase + 0] = fsum0;
    red[nh][rbase + 1] = fsum1;
    red[nh][rbase + 2] = fsum2;
    red[nh][rbase + 3] = fsum3;
  }
  __syncthreads();
  if (t < 32) {
    ftT[(size_t)b * S_ + s0 + t] = red[0][t] + red[1][t] + b2[0];
  }
}

// ---------------- finisher: combine partials + logsumexp + output ----------------
__global__ __launch_bounds__(256) void Kfin(const float* __restrict__ ftT,
                                            const float* __restrict__ scal_pwx,
                                            const float* __restrict__ pxw_part,
                                            const float* __restrict__ fzw_part,
                                            const float* __restrict__ b2,
                                            float* __restrict__ out) {
  const int b = blockIdx.x, t = threadIdx.x;
  __shared__ float red[4];
  __shared__ float red2[4];
  const int lane = t & 63, wid = t >> 6;
  const float v = ftT[(size_t)b * S_ + t];
  float m = v;
  #pragma unroll
  for (int o = 1; o < 64; o <<= 1) m = fmaxf(m, __shfl_xor(m, o));
  if (lane == 0) red[wid] = m;
  __syncthreads();
  m = fmaxf(fmaxf(red[0], red[1]), fmaxf(red[2], red[3]));
  float e = expf(v - m);
  #pragma unroll
  for (int o = 1; o < 64; o <<= 1) e += __shfl_xor(e, o);
  if (lane == 0) red2[wid] = e;
  __syncthreads();
  if (t == 0) {
    const float tot = red2[0] + red2[1] + red2[2] + red2[3];
    const float logZ = m + logf(tot) - logf((float)S_) + (float)D_ * logf(2.f);
    const float pxw = pxw_part[b * 4] + pxw_part[b * 4 + 1] + pxw_part[b * 4 + 2] + pxw_part[b * 4 + 3];
    const float fzw = fzw_part[b * 8] + fzw_part[b * 8 + 1] + fzw_part[b * 8 + 2] + fzw_part[b * 8 + 3]
                    + fzw_part[b * 8 + 4] + fzw_part[b * 8 + 5] + fzw_part[b * 8 + 6] + fzw_part[b * 8 + 7]
                    + b2[0];
    const float pwx = scal_pwx[b];
    const float r_wz = fminf(fzw - logZ, 0.f);
    out[b] = -(pxw - pwx + r_wz);
  }
}

extern "C" void kernel_launch(void* const* d_in, const int* in_sizes, int n_in,
                              void* d_out, int out_size, void* d_ws, size_t ws_size,
                              hipStream_t stream) {
  const float* x    = (const float*)d_in[0];
  // d_in[1] = y, unused
  const float* w    = (const float*)d_in[2];
  const float* z    = (const float*)d_in[3];
  const float* wt   = (const float*)d_in[4];
  const float* W    = (const float*)d_in[5];
  const float* bvec = (const float*)d_in[6];
  const float* cvec = (const float*)d_in[7];
  const float* W1   = (const float*)d_in[8];
  const float* b1   = (const float*)d_in[9];
  const float* W2   = (const float*)d_in[10];
  const float* b2   = (const float*)d_in[11];

  float* ws_f = (float*)d_ws;
  float* zb1            = ws_f;                       // 65536 f
  float* ftT            = ws_f + 65536;               // 32768 f
  unsigned short* W1wb  = (unsigned short*)(ws_f + 98304);   // 65536 ushort (32768 f)
  float* scal_pwx       = ws_f + 131072;              // 128 f
  float* pxw_part       = ws_f + 131200;              // 512 f
  float* fzw_part       = ws_f + 131712;              // 1024 f
  float* out = (float*)d_out;

  hipLaunchKernelGGL(Kconv, dim3(256), dim3(256), 0, stream, W1, W1wb);
  hipLaunchKernelGGL(K_pwx, dim3(B_), dim3(1024), 0, stream, x, w, W, bvec, scal_pwx);
  hipLaunchKernelGGL(K_pxw, dim3(512), dim3(256), 0, stream, x, w, W, cvec, pxw_part);
  hipLaunchKernelGGL(K_zw, dim3(256), dim3(256), 0, stream, z, w, W1, b1, W2, zb1, fzw_part);
  hipLaunchKernelGGL(K_mfma, dim3((S_ / 32) * B_), dim3(256), 0, stream,
                     wt, W1wb, zb1, W2, b2, ftT);
  hipLaunchKernelGGL(Kfin, dim3(B_), dim3(256), 0, stream, ftT, scal_pwx, pxw_part, fzw_part, b2, out);
}

// Round 3
// 40.767 us; speedup vs baseline: 3.5192x; 1.7141x over previous
//
#include <hip/hip_runtime.h>
#include <hip/hip_bf16.h>
#include <math.h>

#define B_ 128
#define IN_ 1024
#define D_ 128
#define H_ 512
#define S_ 256

typedef __attribute__((ext_vector_type(8))) short short8v;
typedef __attribute__((ext_vector_type(8))) unsigned short ushort8v;
typedef __attribute__((ext_vector_type(4))) unsigned short ushort4v;
typedef __attribute__((ext_vector_type(4))) float f32x4;

__device__ __forceinline__ float softplusf(float x) {
  return fmaxf(x, 0.f) + log1pf(expf(-fabsf(x)));
}

__device__ __forceinline__ unsigned short f2bf(float f) {
  unsigned u = __float_as_uint(f);
  unsigned r = (u + 0x7fff + ((u >> 16) & 1)) >> 16;   // RNE
  return (unsigned short)r;
}

// ============ fused prep kernel, block-range dispatch ============
// [0,64)     : pack W1 w-half -> bf16 in MFMA-fragment order Bp[frag][lane][j]
// [64,576)   : log_pwx partial logits  (b x kc-of-4)
// [576,1088) : log_pxw partials        (b x ic-of-4)
// [1088,1344): zb1 + f_zw partials     (b-quad x hc-of-8)
__global__ __launch_bounds__(256) void Kprep(
    const float* __restrict__ x, const float* __restrict__ w,
    const float* __restrict__ z, const float* __restrict__ W,
    const float* __restrict__ cvec, const float* __restrict__ W1,
    const float* __restrict__ b1, const float* __restrict__ W2,
    unsigned short* __restrict__ Bp, float* __restrict__ l2part,
    float* __restrict__ pxw_part, float* __restrict__ zb1,
    float* __restrict__ fzw_part) {
  __shared__ float smem[1024];
  const int blk = blockIdx.x;
  const int t = threadIdx.x;

  if (blk < 64) {
    // ---- pack Bp: Bp[frag*512 + l*8 + j] = bf16(W1w[h][k]),
    // frag=(hblk)*4+ks, h=hblk*16+(l&15), k=ks*32+(l>>4)*8+j
    const int o = (blk * 256 + t) * 4;
    const int frag = o >> 9;
    const int l = (o >> 3) & 63;
    const int j0 = o & 7;             // 0 or 4
    const int h = (frag >> 2) * 16 + (l & 15);
    const int k0 = (frag & 3) * 32 + ((l >> 4) << 3) + j0;
    const float4 v = *(const float4*)(W1 + (size_t)h * 256 + 128 + k0);
    ushort4v u;
    u[0] = f2bf(v.x); u[1] = f2bf(v.y); u[2] = f2bf(v.z); u[3] = f2bf(v.w);
    *(ushort4v*)(Bp + o) = u;
  } else if (blk < 576) {
    // ---- pwx partial: logits2_part[(b*4+kc)][d] = sum over 256-i chunk
    const int bb = blk - 64;
    const int b = bb >> 2, kc = bb & 3;
    float* xs = smem;            // 256
    float* p2 = smem + 256;      // 256
    xs[t] = x[b * IN_ + kc * 256 + t];
    __syncthreads();
    const int d = t & 127, ks = t >> 7;
    const float* __restrict__ Wp = W + (size_t)(kc * 256 + ks * 128) * D_ + d;
    float s = 0.f;
    #pragma unroll 8
    for (int i = 0; i < 128; ++i) s = fmaf(xs[ks * 128 + i], Wp[(size_t)i * D_], s);
    p2[ks * 128 + d] = s;
    __syncthreads();
    if (t < 128) l2part[((size_t)b * 4 + kc) * 128 + t] = p2[t] + p2[128 + t];
  } else if (blk < 1088) {
    // ---- pxw partial
    const int bb = blk - 576;
    const int b = bb >> 2, ic = bb & 3;
    float* ws_ = smem;           // 128
    float* red = smem + 128;     // 4
    if (t < 128) ws_[t] = w[b * 128 + t];
    __syncthreads();
    const int i = ic * 256 + t;
    const float4* __restrict__ row = (const float4*)(W + (size_t)i * D_);
    float a0 = 0.f, a1 = 0.f, a2 = 0.f, a3 = 0.f;
    #pragma unroll
    for (int q = 0; q < 32; ++q) {
      const float4 v = row[q];
      a0 = fmaf(v.x, ws_[4 * q + 0], a0);
      a1 = fmaf(v.y, ws_[4 * q + 1], a1);
      a2 = fmaf(v.z, ws_[4 * q + 2], a2);
      a3 = fmaf(v.w, ws_[4 * q + 3], a3);
    }
    const float lg = cvec[i] + ((a0 + a1) + (a2 + a3));
    float term = x[b * IN_ + i] * lg - softplusf(lg);
    #pragma unroll
    for (int o = 32; o > 0; o >>= 1) term += __shfl_down(term, o);
    const int lane = t & 63, wid = t >> 6;
    if (lane == 0) red[wid] = term;
    __syncthreads();
    if (t == 0) pxw_part[b * 4 + ic] = red[0] + red[1] + red[2] + red[3];
  } else {
    // ---- zw: zb1 + fzw partials
    const int bb = blk - 1088;
    const int bq = bb >> 3, hc = bb & 7;
    float* zs  = smem;           // 512  (4 b x 128 d)
    float* ws2 = smem + 512;     // 512
    for (int e = t; e < 512; e += 256) {
      zs[e]  = z[bq * 512 + e];
      ws2[e] = w[bq * 512 + e];
    }
    __syncthreads();
    const int bs = t >> 6, hl = t & 63;
    const int b = bq * 4 + bs, h = hc * 64 + hl;
    const float4* __restrict__ row = (const float4*)(W1 + (size_t)h * 256);
    float zp = b1[h], wp = 0.f;
    #pragma unroll
    for (int q = 0; q < 32; ++q) {
      const float4 v = row[q];
      zp = fmaf(v.x, zs[bs * 128 + 4 * q + 0], zp);
      zp = fmaf(v.y, zs[bs * 128 + 4 * q + 1], zp);
      zp = fmaf(v.z, zs[bs * 128 + 4 * q + 2], zp);
      zp = fmaf(v.w, zs[bs * 128 + 4 * q + 3], zp);
    }
    #pragma unroll
    for (int q = 32; q < 64; ++q) {
      const float4 v = row[q];
      wp = fmaf(v.x, ws2[bs * 128 + 4 * (q - 32) + 0], wp);
      wp = fmaf(v.y, ws2[bs * 128 + 4 * (q - 32) + 1], wp);
      wp = fmaf(v.z, ws2[bs * 128 + 4 * (q - 32) + 2], wp);
      wp = fmaf(v.w, ws2[bs * 128 + 4 * (q - 32) + 3], wp);
    }
    zb1[(size_t)b * H_ + h] = zp;
    float fp = fmaxf(zp + wp, 0.f) * W2[h];
    #pragma unroll
    for (int o = 1; o < 64; o <<= 1) fp += __shfl_xor(fp, o);
    if (hl == 0) fzw_part[b * 8 + hc] = fp;
  }
}

// ============ big GEMM via MFMA ============
// block = (b, 64 s-rows). 4 waves = (nh = wave>>1, nt-half = wave&1).
// Each wave: 4 m-tiles x 8 nt x 4 ks MFMA; B loaded once per (nt,ks), reused x4.
__global__ __launch_bounds__(256) void Kmfma(
    const float* __restrict__ wt, const unsigned short* __restrict__ Bp,
    const float* __restrict__ zb1, const float* __restrict__ W2,
    const float* __restrict__ b2, float* __restrict__ ftT) {
  const int blk = blockIdx.x;          // 512
  const int b = blk & (B_ - 1);
  const int sc = blk >> 7;             // 0..3
  const int s0 = sc * 64;
  const int t = threadIdx.x;
  const int lane = t & 63, wave = t >> 6;
  const int nh = wave >> 1, nth = wave & 1;

  __shared__ unsigned short atile[64 * 128];   // 16 KB, XOR-swizzled
  __shared__ float zb1s[H_];
  __shared__ float w2s[H_];
  __shared__ float red[4][64];

  zb1s[t] = zb1[(size_t)b * H_ + t];
  zb1s[256 + t] = zb1[(size_t)b * H_ + 256 + t];
  w2s[t] = W2[t];
  w2s[256 + t] = W2[256 + t];

  // stage A: 64 rows x 128 d, fp32 -> bf16, granule swizzle g ^= r&15
  {
    const int r = t >> 2;              // 0..63
    const int g0 = (t & 3) * 4;
    const float* __restrict__ src = wt + ((size_t)(s0 + r) * B_ + b) * D_;
    #pragma unroll
    for (int gg = 0; gg < 4; ++gg) {
      const int g = g0 + gg;
      const float4 v0 = *(const float4*)(src + g * 8);
      const float4 v1 = *(const float4*)(src + g * 8 + 4);
      ushort8v u;
      u[0] = f2bf(v0.x); u[1] = f2bf(v0.y); u[2] = f2bf(v0.z); u[3] = f2bf(v0.w);
      u[4] = f2bf(v1.x); u[5] = f2bf(v1.y); u[6] = f2bf(v1.z); u[7] = f2bf(v1.w);
      *(ushort8v*)&atile[r * 128 + ((g ^ (r & 15)) << 3)] = u;
    }
  }
  __syncthreads();

  // A fragments: row = m*16 + (lane&15), k = ks*32 + (lane>>4)*8 + j
  short8v afr[4][4];
  #pragma unroll
  for (int m = 0; m < 4; ++m) {
    const int arow = m * 16 + (lane & 15);
    #pragma unroll
    for (int ks = 0; ks < 4; ++ks) {
      const int g = ks * 4 + (lane >> 4);
      afr[m][ks] = *(const short8v*)&atile[arow * 128 + ((g ^ (arow & 15)) << 3)];
    }
  }

  float fsum[4][4];
  #pragma unroll
  for (int m = 0; m < 4; ++m)
    #pragma unroll
    for (int j = 0; j < 4; ++j) fsum[m][j] = 0.f;

  const int hl = lane & 15;
  #pragma unroll 2
  for (int nt2 = 0; nt2 < 8; ++nt2) {
    const int nt = nth * 8 + nt2;
    const int hrow = nh * 256 + nt * 16 + hl;
    f32x4 acc0 = {0.f,0.f,0.f,0.f}, acc1 = {0.f,0.f,0.f,0.f};
    f32x4 acc2 = {0.f,0.f,0.f,0.f}, acc3 = {0.f,0.f,0.f,0.f};
    #pragma unroll
    for (int ks = 0; ks < 4; ++ks) {
      const int frag = (nh * 16 + nt) * 4 + ks;
      const short8v bfr = *(const short8v*)(Bp + ((size_t)frag << 9) + (lane << 3));
      acc0 = __builtin_amdgcn_mfma_f32_16x16x32_bf16(afr[0][ks], bfr, acc0, 0, 0, 0);
      acc1 = __builtin_amdgcn_mfma_f32_16x16x32_bf16(afr[1][ks], bfr, acc1, 0, 0, 0);
      acc2 = __builtin_amdgcn_mfma_f32_16x16x32_bf16(afr[2][ks], bfr, acc2, 0, 0, 0);
      acc3 = __builtin_amdgcn_mfma_f32_16x16x32_bf16(afr[3][ks], bfr, acc3, 0, 0, 0);
    }
    const float zv = zb1s[hrow], wv = w2s[hrow];
    #pragma unroll
    for (int j = 0; j < 4; ++j) {
      fsum[0][j] += fmaxf(acc0[j] + zv, 0.f) * wv;
      fsum[1][j] += fmaxf(acc1[j] + zv, 0.f) * wv;
      fsum[2][j] += fmaxf(acc2[j] + zv, 0.f) * wv;
      fsum[3][j] += fmaxf(acc3[j] + zv, 0.f) * wv;
    }
  }
  // reduce over the 16 h-columns (lane bits 0..3)
  #pragma unroll
  for (int m = 0; m < 4; ++m)
    #pragma unroll
    for (int j = 0; j < 4; ++j) {
      float v = fsum[m][j];
      v += __shfl_xor(v, 1); v += __shfl_xor(v, 2);
      v += __shfl_xor(v, 4); v += __shfl_xor(v, 8);
      fsum[m][j] = v;
    }
  if (hl == 0) {
    const int rb = (lane >> 4) * 4;
    #pragma unroll
    for (int m = 0; m < 4; ++m)
      #pragma unroll
      for (int j = 0; j < 4; ++j)
        red[wave][m * 16 + rb + j] = fsum[m][j];
  }
  __syncthreads();
  if (t < 64)
    ftT[(size_t)b * S_ + s0 + t] = red[0][t] + red[1][t] + red[2][t] + red[3][t] + b2[0];
}

// ============ finisher ============
__global__ __launch_bounds__(256) void Kfin(
    const float* __restrict__ ftT, const float* __restrict__ l2part,
    const float* __restrict__ bvec, const float* __restrict__ w,
    const float* __restrict__ pxw_part, const float* __restrict__ fzw_part,
    const float* __restrict__ b2, float* __restrict__ out) {
  const int b = blockIdx.x, t = threadIdx.x;
  __shared__ float red[4], red2[4], red3[4];
  const int lane = t & 63, wid = t >> 6;
  // logsumexp over ftT[b][:]
  const float v = ftT[(size_t)b * S_ + t];
  float m = v;
  #pragma unroll
  for (int o = 1; o < 64; o <<= 1) m = fmaxf(m, __shfl_xor(m, o));
  if (lane == 0) red[wid] = m;
  __syncthreads();
  m = fmaxf(fmaxf(red[0], red[1]), fmaxf(red[2], red[3]));
  float e = expf(v - m);
  #pragma unroll
  for (int o = 1; o < 64; o <<= 1) e += __shfl_xor(e, o);
  if (lane == 0) red2[wid] = e;
  // log_pwx from partial logits
  float term = 0.f;
  if (t < 128) {
    float lg = bvec[t];
    #pragma unroll
    for (int kc = 0; kc < 4; ++kc) lg += l2part[((size_t)b * 4 + kc) * 128 + t];
    term = w[b * 128 + t] * lg - softplusf(lg);
  }
  #pragma unroll
  for (int o = 32; o > 0; o >>= 1) term += __shfl_down(term, o);
  if (lane == 0) red3[wid] = term;
  __syncthreads();
  if (t == 0) {
    const float tot = red2[0] + red2[1] + red2[2] + red2[3];
    const float logZ = m + logf(tot) - logf((float)S_) + (float)D_ * logf(2.f);
    const float pwx = red3[0] + red3[1] + red3[2] + red3[3];
    const float pxw = pxw_part[b * 4] + pxw_part[b * 4 + 1]
                    + pxw_part[b * 4 + 2] + pxw_part[b * 4 + 3];
    const float fzw = fzw_part[b * 8 + 0] + fzw_part[b * 8 + 1] + fzw_part[b * 8 + 2]
                    + fzw_part[b * 8 + 3] + fzw_part[b * 8 + 4] + fzw_part[b * 8 + 5]
                    + fzw_part[b * 8 + 6] + fzw_part[b * 8 + 7] + b2[0];
    const float r_wz = fminf(fzw - logZ, 0.f);
    out[b] = -(pxw - pwx + r_wz);
  }
}

extern "C" void kernel_launch(void* const* d_in, const int* in_sizes, int n_in,
                              void* d_out, int out_size, void* d_ws, size_t ws_size,
                              hipStream_t stream) {
  const float* x    = (const float*)d_in[0];
  // d_in[1] = y, unused
  const float* w    = (const float*)d_in[2];
  const float* z    = (const float*)d_in[3];
  const float* wt   = (const float*)d_in[4];
  const float* W    = (const float*)d_in[5];
  const float* bvec = (const float*)d_in[6];
  const float* cvec = (const float*)d_in[7];
  const float* W1   = (const float*)d_in[8];
  const float* b1   = (const float*)d_in[9];
  const float* W2   = (const float*)d_in[10];
  const float* b2   = (const float*)d_in[11];

  float* ws_f = (float*)d_ws;
  float* zb1            = ws_f;                              // 65536 f
  float* ftT            = ws_f + 65536;                      // 32768 f
  unsigned short* Bp    = (unsigned short*)(ws_f + 98304);   // 65536 us
  float* l2part         = ws_f + 131072;                     // 65536 f
  float* pxw_part       = ws_f + 196608;                     // 512 f
  float* fzw_part       = ws_f + 197120;                     // 1024 f
  float* out = (float*)d_out;

  hipLaunchKernelGGL(Kprep, dim3(1344), dim3(256), 0, stream,
                     x, w, z, W, cvec, W1, b1, W2, Bp, l2part, pxw_part, zb1, fzw_part);
  hipLaunchKernelGGL(Kmfma, dim3(4 * B_), dim3(256), 0, stream,
                     wt, Bp, zb1, W2, b2, ftT);
  hipLaunchKernelGGL(Kfin, dim3(B_), dim3(256), 0, stream,
                     ftT, l2part, bvec, w, pxw_part, fzw_part, b2, out);
}